// Round 8
// baseline (141.671 us; speedup 1.0000x reference)
//
#include <hip/hip_runtime.h>
#include <cstddef>

static constexpr int TT = 64;    // decoder steps
static constexpr int BB = 8;     // batch
static constexpr int SS = 512;   // source length
static constexpr int HH = 512;   // hidden

typedef __attribute__((ext_vector_type(8))) short bf16x8;
typedef __attribute__((ext_vector_type(4))) float f32x4;

__device__ __forceinline__ float fast_tanh(float x) {
  float e = __expf(2.0f * x);
  return 1.0f - 2.0f * __builtin_amdgcn_rcpf(e + 1.0f);
}
__device__ __forceinline__ unsigned short f2bf(float f) {
  unsigned u = __float_as_uint(f);
  return (unsigned short)((u + 0x7FFFu + ((u >> 16) & 1u)) >> 16);   // RNE
}

// ---------------------------------------------------------------------------
// k_prep — all preprocessing, vectorized (float4/ushort4):
//  [0,2048):     encpb = bf16(tanh(enc + cov*wcov)), 2 bs-rows/block
//  [2048,2304):  dec pack -> concatb right half, 2 m-rows/block
//  [2304,3328):  weight transposes Wq,Wc,Wo (32x32 tiles -> WT[n][k] bf16)
// ---------------------------------------------------------------------------
__global__ __launch_bounds__(256)
void k_prep(const float* __restrict__ enc, const float* __restrict__ cov,
            const float* __restrict__ wcov, const float* __restrict__ dec,
            const float* __restrict__ Wq, const float* __restrict__ Wc,
            const float* __restrict__ Wo,
            unsigned short* __restrict__ encpb, unsigned short* __restrict__ concatb,
            unsigned short* __restrict__ WqT, unsigned short* __restrict__ WcT,
            unsigned short* __restrict__ WoT) {
  __shared__ float tile[32][33];
  const int blk = blockIdx.x, tid = threadIdx.x;

  if (blk < 2048) {
    const int r = tid >> 7, c = (tid & 127) * 4;
    const int bs = blk * 2 + r;
    const int s = bs & 511, b = bs >> 9;
    const float4 ev = *(const float4*)(enc + (size_t)(s * BB + b) * HH + c);
    const float cv = cov[bs];
    const float4 wv = *(const float4*)(wcov + c);
    ushort4 o;
    o.x = f2bf(fast_tanh(ev.x + cv * wv.x));
    o.y = f2bf(fast_tanh(ev.y + cv * wv.y));
    o.z = f2bf(fast_tanh(ev.z + cv * wv.z));
    o.w = f2bf(fast_tanh(ev.w + cv * wv.w));
    *(ushort4*)(encpb + (size_t)bs * HH + c) = o;
  } else if (blk < 2304) {
    const int r = tid >> 7, c = (tid & 127) * 4;
    const int m = (blk - 2048) * 2 + r, t = m & 63, b = m >> 6;   // m = b*64+t
    const float4 dv = *(const float4*)(dec + (size_t)(t * BB + b) * HH + c);
    ushort4 o;
    o.x = f2bf(dv.x); o.y = f2bf(dv.y); o.z = f2bf(dv.z); o.w = f2bf(dv.w);
    *(ushort4*)(concatb + (size_t)m * 1024 + 512 + c) = o;
  } else {
    int l = blk - 2304;
    const float* W; unsigned short* WT; int KT;
    if (l < 256)      { W = Wq; WT = WqT; KT = 512; }
    else if (l < 512) { W = Wc; WT = WcT; KT = 512; l -= 256; }
    else              { W = Wo; WT = WoT; KT = 1024; l -= 512; }
    const int n0 = (l & 15) * 32, k0 = (l >> 4) * 32;
    const int r = tid >> 3, c4 = (tid & 7) * 4;
    const float4 w = *(const float4*)(W + (size_t)(k0 + r) * 512 + n0 + c4);
    tile[r][c4 + 0] = w.x; tile[r][c4 + 1] = w.y;
    tile[r][c4 + 2] = w.z; tile[r][c4 + 3] = w.w;
    __syncthreads();
    unsigned short* o = WT + (size_t)(n0 + r) * KT + k0 + c4;
#pragma unroll
    for (int i = 0; i < 4; ++i) o[i] = f2bf(tile[c4 + i][r]);
  }
}

// ---------------------------------------------------------------------------
// 64x64 bf16 MFMA tile over K range. 256 thr / 4 waves.
// C/D layout: col=lane&15, row=(lane>>4)*4+reg (verified r2..r7).
// ---------------------------------------------------------------------------
template<int LDA, int LDB>
__device__ __forceinline__ void gemm_tile(const unsigned short* __restrict__ A,
                                          const unsigned short* __restrict__ BT,
                                          int m0, int n0, int kbeg, int kend,
                                          unsigned short (*As)[72],
                                          unsigned short (*Bs)[72],
                                          f32x4 acc[4]) {
  const int tid = threadIdx.x, w = tid >> 6, lane = tid & 63;
  const int lr = tid >> 2, lk = (tid & 3) * 16;
  const int fm = w * 16 + (lane & 15), fk = (lane >> 4) * 8;
  for (int k0 = kbeg; k0 < kend; k0 += 64) {
    const uint4* ga = (const uint4*)(A + (size_t)(m0 + lr) * LDA + k0 + lk);
    const uint4* gb = (const uint4*)(BT + (size_t)(n0 + lr) * LDB + k0 + lk);
    uint4 a0 = ga[0], a1 = ga[1], b0 = gb[0], b1 = gb[1];
    *(uint4*)&As[lr][lk] = a0;  *(uint4*)&As[lr][lk + 8] = a1;
    *(uint4*)&Bs[lr][lk] = b0;  *(uint4*)&Bs[lr][lk + 8] = b1;
    __syncthreads();
#pragma unroll
    for (int ks = 0; ks < 2; ++ks) {
      bf16x8 af = *(const bf16x8*)&As[fm][ks * 32 + fk];
#pragma unroll
      for (int j = 0; j < 4; ++j) {
        bf16x8 bf = *(const bf16x8*)&Bs[j * 16 + (lane & 15)][ks * 32 + fk];
        acc[j] = __builtin_amdgcn_mfma_f32_16x16x32_bf16(af, bf, acc[j], 0, 0, 0);
      }
    }
    __syncthreads();
  }
}

// ---------------------------------------------------------------------------
// k_gemm12 — three GEMM jobs in ONE launch (640 blocks):
//  g <  64: Ea1 = exp(2*clamp(dec@Wq + bq))
//  g < 576: Ea2 = exp(2*clamp(encp@Wc))
//  g < 640: attn_h base = dec@Wo_bot + bo (scattered [T,B,H]); k_attn adds c@Wo_top
// ---------------------------------------------------------------------------
__global__ __launch_bounds__(256)
void k_gemm12(const unsigned short* __restrict__ concatb,
              const unsigned short* __restrict__ encpb,
              const unsigned short* __restrict__ WqT,
              const unsigned short* __restrict__ WcT,
              const unsigned short* __restrict__ WoT,
              const float* __restrict__ bq, const float* __restrict__ bo,
              float* __restrict__ Ea1, float* __restrict__ Ea2,
              float* __restrict__ attn_h) {
  __shared__ unsigned short As[64][72];
  __shared__ unsigned short Bs[64][72];
  const int g = blockIdx.x, tid = threadIdx.x;
  const int w = tid >> 6, lane = tid & 63;
  const int col = lane & 15, rq = lane >> 4;

  if (g < 64) {                        // a1
    const int m0 = (g >> 3) * 64, n0 = (g & 7) * 64;
    f32x4 acc[4] = {};
    gemm_tile<1024, 512>(concatb + 512, WqT, m0, n0, 0, 512, As, Bs, acc);
#pragma unroll
    for (int j = 0; j < 4; ++j) {
      const int n = n0 + j * 16 + col;
      const float bv = bq[n];
#pragma unroll
      for (int r = 0; r < 4; ++r) {
        const int m = m0 + w * 16 + rq * 4 + r;
        // clamp +-30: downstream product may hit inf; rcp(inf)=0 is the exact
        // tanh=+-1 limit; no NaN path (factors positive finite).
        float val = fminf(fmaxf(acc[j][r] + bv, -30.0f), 30.0f);
        Ea1[(size_t)m * 512 + n] = __expf(2.0f * val);
      }
    }
  } else if (g < 576) {                // a2
    const int u = g - 64;
    const int m0 = (u >> 3) * 64, n0 = (u & 7) * 64;
    f32x4 acc[4] = {};
    gemm_tile<512, 512>(encpb, WcT, m0, n0, 0, 512, As, Bs, acc);
#pragma unroll
    for (int j = 0; j < 4; ++j) {
      const int n = n0 + j * 16 + col;
#pragma unroll
      for (int r = 0; r < 4; ++r) {
        const int m = m0 + w * 16 + rq * 4 + r;
        float val = fminf(fmaxf(acc[j][r], -30.0f), 30.0f);
        Ea2[(size_t)m * 512 + n] = __expf(2.0f * val);
      }
    }
  } else {                             // attn_h base = dec@Wo_bot + bo
    const int u = g - 576;
    const int m0 = (u >> 3) * 64, n0 = (u & 7) * 64;
    f32x4 acc[4] = {};
    gemm_tile<1024, 1024>(concatb, WoT, m0, n0, 512, 1024, As, Bs, acc);
#pragma unroll
    for (int j = 0; j < 4; ++j) {
      const int n = n0 + j * 16 + col;
      const float bv = bo[n];
#pragma unroll
      for (int r = 0; r < 4; ++r) {
        const int m = m0 + w * 16 + rq * 4 + r;
        const int bi = m >> 6, t = m & 63;
        attn_h[(size_t)(t * BB + bi) * 512 + n] = acc[j][r] + bv;
      }
    }
  }
}

// ---------------------------------------------------------------------------
// k_attn — scores + softmax + context + output-GEMM fused.
// 256 blocks (b, t-pair), 512 thr (8 waves).
// Scores: sc[t,s] = -(sum_h 2 v_h / (Ea1*Ea2+1))  [shift-invariant softmax].
// Context c[2][512] combined in LDS (bf16) -> in-block MFMA with WoT top half:
// A-frag lanes m=lane&15<2 carry c rows, rest zero (MFMA waste is ~free);
// D rows 0,1 (lane<16, reg 0..1) do exclusive read-add-write on attn_h base.
// ---------------------------------------------------------------------------
__global__ __launch_bounds__(512)
void k_attn(const float* __restrict__ Ea1, const float* __restrict__ Ea2,
            const float* __restrict__ v, const unsigned short* __restrict__ encpb,
            const unsigned short* __restrict__ WoT,
            float* __restrict__ align_out, float* __restrict__ attn_h) {
  __shared__ __align__(16) char smem[14400];
  float (*sc)[512]   = (float(*)[512])smem;            // [2][512] scores->align
  float (*ea1s)[512] = (float(*)[512])(smem + 4096);   // [2][512] (scores phase)
  float* v2s         = (float*)(smem + 8192);          // [512]    (scores phase)
  float2* part       = (float2*)(smem + 4096);         // [2][2][256] (ctx phase)
  unsigned short* c2b = (unsigned short*)(smem + 12288); // [2][512] bf16 c rows
  float (*red)[8]    = (float(*)[8])(smem + 14336);    // [2][8]

  const int g = blockIdx.x, tid = threadIdx.x;
  const int b = g & 7, t0 = (g >> 3) * 2;              // XCD-affine b
  const int wv = tid >> 6, lane = tid & 63;
  const int hq = lane & 3, sl = lane >> 2;

  ea1s[0][tid] = Ea1[(size_t)(b * TT + t0) * HH + tid];
  ea1s[1][tid] = Ea1[(size_t)(b * TT + t0 + 1) * HH + tid];
  v2s[tid] = 2.0f * v[tid];
  __syncthreads();

  // ---- scores: 8 waves x 32 s per pass, 2 passes ----
#define TERM(E1, E2, VV, A) A = fmaf(VV, __builtin_amdgcn_rcpf(fmaf(E1, E2, 1.0f)), A)
  for (int p = 0; p < 2; ++p) {
    const int s0 = p * 256 + wv * 32 + sl;             // and s0+16
    const float* e2p0 = Ea2 + (size_t)(b * SS + s0) * HH;
    const float* e2p1 = e2p0 + (size_t)16 * HH;
    float acc[2][2] = {};
#pragma unroll 4
    for (int it = 0; it < 32; ++it) {
      const int h = it * 16 + hq * 4;
      const float4 e20 = *(const float4*)(e2p0 + h);
      const float4 e21 = *(const float4*)(e2p1 + h);
      const float4 vvv = *(const float4*)&v2s[h];
      float4 e1r[2];
      e1r[0] = *(const float4*)&ea1s[0][h];
      e1r[1] = *(const float4*)&ea1s[1][h];
#pragma unroll
      for (int i = 0; i < 2; ++i) {
        TERM(e1r[i].x, e20.x, vvv.x, acc[i][0]);
        TERM(e1r[i].y, e20.y, vvv.y, acc[i][0]);
        TERM(e1r[i].z, e20.z, vvv.z, acc[i][0]);
        TERM(e1r[i].w, e20.w, vvv.w, acc[i][0]);
        TERM(e1r[i].x, e21.x, vvv.x, acc[i][1]);
        TERM(e1r[i].y, e21.y, vvv.y, acc[i][1]);
        TERM(e1r[i].z, e21.z, vvv.z, acc[i][1]);
        TERM(e1r[i].w, e21.w, vvv.w, acc[i][1]);
      }
    }
#pragma unroll
    for (int i = 0; i < 2; ++i)
#pragma unroll
      for (int j = 0; j < 2; ++j) {
        acc[i][j] += __shfl_xor(acc[i][j], 1);
        acc[i][j] += __shfl_xor(acc[i][j], 2);
      }
    if (hq == 0) {
      sc[0][s0] = -acc[0][0]; sc[0][s0 + 16] = -acc[0][1];
      sc[1][s0] = -acc[1][0]; sc[1][s0 + 16] = -acc[1][1];
    }
  }
#undef TERM
  __syncthreads();

  // ---- softmax over s (thread owns s=tid for both t's) ----
  const float x0 = sc[0][tid], x1 = sc[1][tid];
  float m0 = x0, m1 = x1;
#pragma unroll
  for (int off = 32; off; off >>= 1) {
    m0 = fmaxf(m0, __shfl_xor(m0, off));
    m1 = fmaxf(m1, __shfl_xor(m1, off));
  }
  if (lane == 0) { red[0][wv] = m0; red[1][wv] = m1; }
  __syncthreads();
  m0 = red[0][0]; m1 = red[1][0];
#pragma unroll
  for (int w2 = 1; w2 < 8; ++w2) { m0 = fmaxf(m0, red[0][w2]); m1 = fmaxf(m1, red[1][w2]); }
  __syncthreads();
  const float e0 = __expf(x0 - m0), e1 = __expf(x1 - m1);
  float s0v = e0, s1v = e1;
#pragma unroll
  for (int off = 32; off; off >>= 1) {
    s0v += __shfl_xor(s0v, off);
    s1v += __shfl_xor(s1v, off);
  }
  if (lane == 0) { red[0][wv] = s0v; red[1][wv] = s1v; }
  __syncthreads();
  float sum0 = 0.f, sum1 = 0.f;
#pragma unroll
  for (int w2 = 0; w2 < 8; ++w2) { sum0 += red[0][w2]; sum1 += red[1][w2]; }
  const float a0 = e0 * __builtin_amdgcn_rcpf(sum0);
  const float a1 = e1 * __builtin_amdgcn_rcpf(sum1);

  align_out[(size_t)(t0 + 0) * BB * SS + b * SS + tid] = a0;
  align_out[(size_t)(t0 + 1) * BB * SS + b * SS + tid] = a1;
  sc[0][tid] = a0;
  sc[1][tid] = a1;
  __syncthreads();

  // ---- context: sh = s-half (waves 0-3 vs 4-7), hp = h-pair ----
  {
    const int sh = tid >> 8, hp = tid & 255;
    const unsigned* ep = (const unsigned*)encpb + (size_t)b * SS * 256;
    float c00 = 0.f, c01 = 0.f, c10 = 0.f, c11 = 0.f;
#pragma unroll 8
    for (int s2 = sh * 256; s2 < sh * 256 + 256; ++s2) {
      const unsigned u = ep[s2 * 256 + hp];
      const float elo = __uint_as_float(u << 16);
      const float ehi = __uint_as_float(u & 0xffff0000u);
      const float av0 = sc[0][s2], av1 = sc[1][s2];
      c00 = fmaf(av0, elo, c00); c01 = fmaf(av0, ehi, c01);
      c10 = fmaf(av1, elo, c10); c11 = fmaf(av1, ehi, c11);
    }
    part[(0 * 2 + sh) * 256 + hp] = make_float2(c00, c01);
    part[(1 * 2 + sh) * 256 + hp] = make_float2(c10, c11);
  }
  __syncthreads();
  {
    const int t = tid >> 8, hp = tid & 255;
    const float2 pa = part[(t * 2 + 0) * 256 + hp];
    const float2 pb = part[(t * 2 + 1) * 256 + hp];
    ((unsigned*)c2b)[t * 256 + hp] =
        (unsigned)f2bf(pa.x + pb.x) | ((unsigned)f2bf(pa.y + pb.y) << 16);
  }
  __syncthreads();

  // ---- output: attn_h rows (t0,b),(t0+1,b) += c @ Wo_top via MFMA ----
  {
    const int n0 = wv * 64;                    // wave covers 64 n
    const int fm = lane & 15, fko = (lane >> 4) * 8;
    f32x4 acc[4] = {};
    for (int k0 = 0; k0 < 512; k0 += 32) {
      bf16x8 af = {};
      if (fm < 2) af = *(const bf16x8*)&c2b[fm * 512 + k0 + fko];
#pragma unroll
      for (int j = 0; j < 4; ++j) {
        const bf16x8 bf = *(const bf16x8*)(WoT +
            (size_t)(n0 + j * 16 + fm) * 1024 + k0 + fko);
        acc[j] = __builtin_amdgcn_mfma_f32_16x16x32_bf16(af, bf, acc[j], 0, 0, 0);
      }
    }
    if (lane < 16) {                           // D rows 0,1 live in lanes 0..15
#pragma unroll
      for (int j = 0; j < 4; ++j) {
        const int n = n0 + j * 16 + lane;
#pragma unroll
        for (int r = 0; r < 2; ++r) {
          float* p = attn_h + (size_t)((t0 + r) * BB + b) * 512 + n;
          *p += acc[j][r];                     // exclusive row ownership
        }
      }
    }
  }
}

// ---------------------------------------------------------------------------
extern "C" void kernel_launch(void* const* d_in, const int* in_sizes, int n_in,
                              void* d_out, int out_size, void* d_ws, size_t ws_size,
                              hipStream_t stream) {
  const float* dec  = (const float*)d_in[0];
  const float* enc  = (const float*)d_in[1];
  const float* cov  = (const float*)d_in[2];
  const float* Wq   = (const float*)d_in[3];
  const float* bq   = (const float*)d_in[4];
  const float* Wc   = (const float*)d_in[5];
  const float* v    = (const float*)d_in[6];
  const float* Wo   = (const float*)d_in[7];
  const float* bo   = (const float*)d_in[8];
  const float* wcov = (const float*)d_in[9];

  float* out = (float*)d_out;
  float* attn_h    = out;                         // [T,B,H]
  float* align_out = out + (size_t)TT * BB * HH;  // [T,B,S]

  char* w = (char*)d_ws;
  const size_t MB = 1024 * 1024;
  unsigned short* encpb   = (unsigned short*)(w);                      // 4 MB
  unsigned short* WqT     = (unsigned short*)(w + 4 * MB);             // 0.5 MB
  unsigned short* WcT     = (unsigned short*)(w + 4 * MB + 512 * 1024);// 0.5 MB
  unsigned short* WoT     = (unsigned short*)(w + 5 * MB);             // 1 MB [n][1024]
  unsigned short* concatb = (unsigned short*)(w + 6 * MB);             // 1 MB [b*64+t][1024]
  float*          Ea1     = (float*)(w + 7 * MB);                      // 1 MB
  float*          Ea2     = (float*)(w + 8 * MB);                      // 8 MB

  k_prep<<<3328, 256, 0, stream>>>(enc, cov, wcov, dec, Wq, Wc, Wo,
                                   encpb, concatb, WqT, WcT, WoT);
  k_gemm12<<<640, 256, 0, stream>>>(concatb, encpb, WqT, WcT, WoT, bq, bo,
                                    Ea1, Ea2, attn_h);
  k_attn<<<256, 512, 0, stream>>>(Ea1, Ea2, v, encpb, WoT, align_out, attn_h);
}

// Round 9
// 126.240 us; speedup vs baseline: 1.1222x; 1.1222x over previous
//
#include <hip/hip_runtime.h>
#include <cstddef>

static constexpr int TT = 64;    // decoder steps
static constexpr int BB = 8;     // batch
static constexpr int SS = 512;   // source length
static constexpr int HH = 512;   // hidden

typedef __attribute__((ext_vector_type(8))) short bf16x8;
typedef __attribute__((ext_vector_type(4))) float f32x4;

__device__ __forceinline__ float fast_tanh(float x) {
  float e = __expf(2.0f * x);
  return 1.0f - 2.0f * __builtin_amdgcn_rcpf(e + 1.0f);
}
__device__ __forceinline__ unsigned short f2bf(float f) {
  unsigned u = __float_as_uint(f);
  return (unsigned short)((u + 0x7FFFu + ((u >> 16) & 1u)) >> 16);   // RNE
}

// ---------------------------------------------------------------------------
// k_prep — all preprocessing, vectorized (float4/ushort4):
//  [0,2048):     encpb = bf16(tanh(enc + cov*wcov)), 2 bs-rows/block
//  [2048,2304):  dec pack -> concatb right half, 2 m-rows/block
//  [2304,3328):  weight transposes Wq,Wc,Wo (32x32 tiles -> WT[n][k] bf16)
// ---------------------------------------------------------------------------
__global__ __launch_bounds__(256)
void k_prep(const float* __restrict__ enc, const float* __restrict__ cov,
            const float* __restrict__ wcov, const float* __restrict__ dec,
            const float* __restrict__ Wq, const float* __restrict__ Wc,
            const float* __restrict__ Wo,
            unsigned short* __restrict__ encpb, unsigned short* __restrict__ concatb,
            unsigned short* __restrict__ WqT, unsigned short* __restrict__ WcT,
            unsigned short* __restrict__ WoT) {
  __shared__ float tile[32][33];
  const int blk = blockIdx.x, tid = threadIdx.x;

  if (blk < 2048) {
    const int r = tid >> 7, c = (tid & 127) * 4;
    const int bs = blk * 2 + r;
    const int s = bs & 511, b = bs >> 9;
    const float4 ev = *(const float4*)(enc + (size_t)(s * BB + b) * HH + c);
    const float cv = cov[bs];
    const float4 wv = *(const float4*)(wcov + c);
    ushort4 o;
    o.x = f2bf(fast_tanh(ev.x + cv * wv.x));
    o.y = f2bf(fast_tanh(ev.y + cv * wv.y));
    o.z = f2bf(fast_tanh(ev.z + cv * wv.z));
    o.w = f2bf(fast_tanh(ev.w + cv * wv.w));
    *(ushort4*)(encpb + (size_t)bs * HH + c) = o;
  } else if (blk < 2304) {
    const int r = tid >> 7, c = (tid & 127) * 4;
    const int m = (blk - 2048) * 2 + r, t = m & 63, b = m >> 6;   // m = b*64+t
    const float4 dv = *(const float4*)(dec + (size_t)(t * BB + b) * HH + c);
    ushort4 o;
    o.x = f2bf(dv.x); o.y = f2bf(dv.y); o.z = f2bf(dv.z); o.w = f2bf(dv.w);
    *(ushort4*)(concatb + (size_t)m * 1024 + 512 + c) = o;
  } else {
    int l = blk - 2304;
    const float* W; unsigned short* WT; int KT;
    if (l < 256)      { W = Wq; WT = WqT; KT = 512; }
    else if (l < 512) { W = Wc; WT = WcT; KT = 512; l -= 256; }
    else              { W = Wo; WT = WoT; KT = 1024; l -= 512; }
    const int n0 = (l & 15) * 32, k0 = (l >> 4) * 32;
    const int r = tid >> 3, c4 = (tid & 7) * 4;
    const float4 w = *(const float4*)(W + (size_t)(k0 + r) * 512 + n0 + c4);
    tile[r][c4 + 0] = w.x; tile[r][c4 + 1] = w.y;
    tile[r][c4 + 2] = w.z; tile[r][c4 + 3] = w.w;
    __syncthreads();
    unsigned short* o = WT + (size_t)(n0 + r) * KT + k0 + c4;
#pragma unroll
    for (int i = 0; i < 4; ++i) o[i] = f2bf(tile[c4 + i][r]);
  }
}

// ---------------------------------------------------------------------------
// 64x64 bf16 MFMA tile over K range. 256 thr / 4 waves.
// C/D layout: col=lane&15, row=(lane>>4)*4+reg (verified r2..r8).
// ---------------------------------------------------------------------------
template<int LDA, int LDB>
__device__ __forceinline__ void gemm_tile(const unsigned short* __restrict__ A,
                                          const unsigned short* __restrict__ BT,
                                          int m0, int n0, int kbeg, int kend,
                                          unsigned short (*As)[72],
                                          unsigned short (*Bs)[72],
                                          f32x4 acc[4]) {
  const int tid = threadIdx.x, w = tid >> 6, lane = tid & 63;
  const int lr = tid >> 2, lk = (tid & 3) * 16;
  const int fm = w * 16 + (lane & 15), fk = (lane >> 4) * 8;
  for (int k0 = kbeg; k0 < kend; k0 += 64) {
    const uint4* ga = (const uint4*)(A + (size_t)(m0 + lr) * LDA + k0 + lk);
    const uint4* gb = (const uint4*)(BT + (size_t)(n0 + lr) * LDB + k0 + lk);
    uint4 a0 = ga[0], a1 = ga[1], b0 = gb[0], b1 = gb[1];
    *(uint4*)&As[lr][lk] = a0;  *(uint4*)&As[lr][lk + 8] = a1;
    *(uint4*)&Bs[lr][lk] = b0;  *(uint4*)&Bs[lr][lk + 8] = b1;
    __syncthreads();
#pragma unroll
    for (int ks = 0; ks < 2; ++ks) {
      bf16x8 af = *(const bf16x8*)&As[fm][ks * 32 + fk];
#pragma unroll
      for (int j = 0; j < 4; ++j) {
        bf16x8 bf = *(const bf16x8*)&Bs[j * 16 + (lane & 15)][ks * 32 + fk];
        acc[j] = __builtin_amdgcn_mfma_f32_16x16x32_bf16(af, bf, acc[j], 0, 0, 0);
      }
    }
    __syncthreads();
  }
}

// ---------------------------------------------------------------------------
// k_gemm12 — three GEMM jobs in ONE launch (640 blocks):
//  g <  64: Ea1 = exp(2*clamp(dec@Wq + bq, +-10.5))
//  g < 576: Ea2 = exp(2*clamp(encp@Wc, +-10.5))
//  g < 640: attn_h base = dec@Wo_bot + bo (scattered [T,B,H]); k_out adds c@Wo_top
// clamp +-10.5: keeps pair-product (Ea1*Ea2+1)^2 <= 2.9e36 (finite, pair-rcp
// safe); tanh(10.5)=1-1.5e-9 so clamping is exact to fp32 tolerance.
// ---------------------------------------------------------------------------
__global__ __launch_bounds__(256)
void k_gemm12(const unsigned short* __restrict__ concatb,
              const unsigned short* __restrict__ encpb,
              const unsigned short* __restrict__ WqT,
              const unsigned short* __restrict__ WcT,
              const unsigned short* __restrict__ WoT,
              const float* __restrict__ bq, const float* __restrict__ bo,
              float* __restrict__ Ea1, float* __restrict__ Ea2,
              float* __restrict__ attn_h) {
  __shared__ unsigned short As[64][72];
  __shared__ unsigned short Bs[64][72];
  const int g = blockIdx.x, tid = threadIdx.x;
  const int w = tid >> 6, lane = tid & 63;
  const int col = lane & 15, rq = lane >> 4;

  if (g < 64) {                        // a1
    const int m0 = (g >> 3) * 64, n0 = (g & 7) * 64;
    f32x4 acc[4] = {};
    gemm_tile<1024, 512>(concatb + 512, WqT, m0, n0, 0, 512, As, Bs, acc);
#pragma unroll
    for (int j = 0; j < 4; ++j) {
      const int n = n0 + j * 16 + col;
      const float bv = bq[n];
#pragma unroll
      for (int r = 0; r < 4; ++r) {
        const int m = m0 + w * 16 + rq * 4 + r;
        float val = fminf(fmaxf(acc[j][r] + bv, -10.5f), 10.5f);
        Ea1[(size_t)m * 512 + n] = __expf(2.0f * val);
      }
    }
  } else if (g < 576) {                // a2
    const int u = g - 64;
    const int m0 = (u >> 3) * 64, n0 = (u & 7) * 64;
    f32x4 acc[4] = {};
    gemm_tile<512, 512>(encpb, WcT, m0, n0, 0, 512, As, Bs, acc);
#pragma unroll
    for (int j = 0; j < 4; ++j) {
      const int n = n0 + j * 16 + col;
#pragma unroll
      for (int r = 0; r < 4; ++r) {
        const int m = m0 + w * 16 + rq * 4 + r;
        float val = fminf(fmaxf(acc[j][r], -10.5f), 10.5f);
        Ea2[(size_t)m * 512 + n] = __expf(2.0f * val);
      }
    }
  } else {                             // attn_h base = dec@Wo_bot + bo
    const int u = g - 576;
    const int m0 = (u >> 3) * 64, n0 = (u & 7) * 64;
    f32x4 acc[4] = {};
    gemm_tile<1024, 1024>(concatb, WoT, m0, n0, 512, 1024, As, Bs, acc);
#pragma unroll
    for (int j = 0; j < 4; ++j) {
      const int n = n0 + j * 16 + col;
      const float bv = bo[n];
#pragma unroll
      for (int r = 0; r < 4; ++r) {
        const int m = m0 + w * 16 + rq * 4 + r;
        const int bi = m >> 6, t = m & 63;
        attn_h[(size_t)(t * BB + bi) * 512 + n] = acc[j][r] + bv;
      }
    }
  }
}

// ---------------------------------------------------------------------------
// k_attn — scores + softmax + context; 256 blocks (b, t-pair), 1024 thr
// (16 waves/CU = 4/SIMD for latency hiding; R8's 8 waves gave VALUBusy 35%).
// Scores (pair-rcp): 2v1/x1 + 2v2/x2 = (2v1*x2 + 2v2*x1)*rcp(x1*x2) — one
// transcendental per TWO elements. sc = -(sum) [softmax shift-invariant].
// Context: 4 s-quarters x 256 h-pairs, LDS combine, bf16 -> concatb left half.
// ---------------------------------------------------------------------------
__global__ __launch_bounds__(1024)
void k_attn(const float* __restrict__ Ea1, const float* __restrict__ Ea2,
            const float* __restrict__ v, const unsigned short* __restrict__ encpb,
            float* __restrict__ align_out, unsigned short* __restrict__ concatb) {
  __shared__ __align__(16) char smem[20544];
  float (*sc)[512]   = (float(*)[512])smem;            // [2][512] scores->align
  float (*ea1s)[512] = (float(*)[512])(smem + 4096);   // [2][512] (scores phase)
  float* v2s         = (float*)(smem + 12288);         // [512]    (scores phase)
  float2* part       = (float2*)(smem + 4096);         // [2][4][256] (ctx phase)
  float (*red)[8]    = (float(*)[8])(smem + 20480);    // [2][8]

  const int g = blockIdx.x, tid = threadIdx.x;
  const int b = g & 7, t0 = (g >> 3) * 2;              // XCD-affine b
  const int wv = tid >> 6, lane = tid & 63;
  const int hq = lane & 3, sl = lane >> 2;

  if (tid < 512) {
    ea1s[0][tid] = Ea1[(size_t)(b * TT + t0) * HH + tid];
    ea1s[1][tid] = Ea1[(size_t)(b * TT + t0 + 1) * HH + tid];
  } else {
    v2s[tid - 512] = 2.0f * v[tid - 512];
  }
  __syncthreads();

  // ---- scores: 16 waves x 32 s, one pass ----
  const int s0 = wv * 32 + sl;                         // and s0+16
  {
    const float* e2p0 = Ea2 + (size_t)(b * SS + s0) * HH;
    const float* e2p1 = e2p0 + (size_t)16 * HH;
    float acc[2][2] = {};
#define PAIR(E1a, E2a, Va, E1b, E2b, Vb, A)                                  \
    {                                                                        \
      const float x1 = fmaf(E1a, E2a, 1.0f), x2 = fmaf(E1b, E2b, 1.0f);      \
      const float rr = __builtin_amdgcn_rcpf(x1 * x2);                       \
      const float nn = fmaf(Va, x2, Vb * x1);                                \
      A = fmaf(nn, rr, A);                                                   \
    }
#pragma unroll 4
    for (int it = 0; it < 32; ++it) {
      const int h = it * 16 + hq * 4;
      const float4 e20 = *(const float4*)(e2p0 + h);
      const float4 e21 = *(const float4*)(e2p1 + h);
      const float4 vvv = *(const float4*)&v2s[h];
      float4 e1r[2];
      e1r[0] = *(const float4*)&ea1s[0][h];
      e1r[1] = *(const float4*)&ea1s[1][h];
#pragma unroll
      for (int i = 0; i < 2; ++i) {
        PAIR(e1r[i].x, e20.x, vvv.x, e1r[i].y, e20.y, vvv.y, acc[i][0]);
        PAIR(e1r[i].z, e20.z, vvv.z, e1r[i].w, e20.w, vvv.w, acc[i][0]);
        PAIR(e1r[i].x, e21.x, vvv.x, e1r[i].y, e21.y, vvv.y, acc[i][1]);
        PAIR(e1r[i].z, e21.z, vvv.z, e1r[i].w, e21.w, vvv.w, acc[i][1]);
      }
    }
#undef PAIR
#pragma unroll
    for (int i = 0; i < 2; ++i)
#pragma unroll
      for (int j = 0; j < 2; ++j) {
        acc[i][j] += __shfl_xor(acc[i][j], 1);
        acc[i][j] += __shfl_xor(acc[i][j], 2);
      }
    if (hq == 0) {
      sc[0][s0] = -acc[0][0]; sc[0][s0 + 16] = -acc[0][1];
      sc[1][s0] = -acc[1][0]; sc[1][s0 + 16] = -acc[1][1];
    }
  }
  __syncthreads();

  // ---- softmax over s (threads < 512 own s=tid; all threads hit barriers) --
  float x0 = 0.f, x1 = 0.f, e0 = 0.f, e1 = 0.f;
  if (tid < 512) {
    x0 = sc[0][tid]; x1 = sc[1][tid];
    float m0 = x0, m1 = x1;
#pragma unroll
    for (int off = 32; off; off >>= 1) {
      m0 = fmaxf(m0, __shfl_xor(m0, off));
      m1 = fmaxf(m1, __shfl_xor(m1, off));
    }
    if (lane == 0) { red[0][wv] = m0; red[1][wv] = m1; }
  }
  __syncthreads();
  {
    float m0 = red[0][0], m1 = red[1][0];
#pragma unroll
    for (int w2 = 1; w2 < 8; ++w2) { m0 = fmaxf(m0, red[0][w2]); m1 = fmaxf(m1, red[1][w2]); }
    __syncthreads();
    if (tid < 512) {
      e0 = __expf(x0 - m0); e1 = __expf(x1 - m1);
      float s0v = e0, s1v = e1;
#pragma unroll
      for (int off = 32; off; off >>= 1) {
        s0v += __shfl_xor(s0v, off);
        s1v += __shfl_xor(s1v, off);
      }
      if (lane == 0) { red[0][wv] = s0v; red[1][wv] = s1v; }
    }
  }
  __syncthreads();
  {
    float sum0 = 0.f, sum1 = 0.f;
#pragma unroll
    for (int w2 = 0; w2 < 8; ++w2) { sum0 += red[0][w2]; sum1 += red[1][w2]; }
    if (tid < 512) {
      const float a0 = e0 * __builtin_amdgcn_rcpf(sum0);
      const float a1 = e1 * __builtin_amdgcn_rcpf(sum1);
      align_out[(size_t)(t0 + 0) * BB * SS + b * SS + tid] = a0;
      align_out[(size_t)(t0 + 1) * BB * SS + b * SS + tid] = a1;
      sc[0][tid] = a0;
      sc[1][tid] = a1;
    }
  }
  __syncthreads();

  // ---- context: q = s-quarter (tid>>8), hp = h-pair (tid&255) ----
  {
    const int q = tid >> 8, hp = tid & 255;
    const unsigned* ep = (const unsigned*)encpb + (size_t)b * SS * 256;
    float c00 = 0.f, c01 = 0.f, c10 = 0.f, c11 = 0.f;
#pragma unroll 8
    for (int s2 = q * 128; s2 < q * 128 + 128; ++s2) {
      const unsigned u = ep[s2 * 256 + hp];
      const float elo = __uint_as_float(u << 16);
      const float ehi = __uint_as_float(u & 0xffff0000u);
      const float av0 = sc[0][s2], av1 = sc[1][s2];
      c00 = fmaf(av0, elo, c00); c01 = fmaf(av0, ehi, c01);
      c10 = fmaf(av1, elo, c10); c11 = fmaf(av1, ehi, c11);
    }
    part[(0 * 4 + q) * 256 + hp] = make_float2(c00, c01);
    part[(1 * 4 + q) * 256 + hp] = make_float2(c10, c11);
  }
  __syncthreads();
  if (tid < 512) {
    const int t = tid >> 8, hp = tid & 255;
    float clo = 0.f, chi = 0.f;
#pragma unroll
    for (int q = 0; q < 4; ++q) {
      const float2 p = part[(t * 4 + q) * 256 + hp];
      clo += p.x; chi += p.y;
    }
    ((unsigned*)concatb)[(size_t)(b * TT + t0 + t) * 512 + hp] =
        (unsigned)f2bf(clo) | ((unsigned)f2bf(chi) << 16);
  }
}

// ---------------------------------------------------------------------------
// k_out — attn_h += c@Wo_top (K=512), split-K x4 via HW fp32 atomics on the
// base (dec@Wo_bot + bo) written by k_gemm12. 256 blocks.
// ---------------------------------------------------------------------------
__global__ __launch_bounds__(256)
void k_out(const unsigned short* __restrict__ A,
           const unsigned short* __restrict__ BT,
           float* __restrict__ C) {
  __shared__ unsigned short As[64][72];
  __shared__ unsigned short Bs[64][72];
  const int tid = threadIdx.x;
  const int w = tid >> 6, lane = tid & 63;
  const int tau = blockIdx.x >> 2, kc = blockIdx.x & 3;
  const int n0 = (tau & 7) * 64, m0 = (tau >> 3) * 64;

  f32x4 acc[4] = {};
  gemm_tile<1024, 1024>(A, BT, m0, n0, kc * 128, kc * 128 + 128, As, Bs, acc);

  const int col = lane & 15, rq = lane >> 4;
#pragma unroll
  for (int j = 0; j < 4; ++j) {
    const int n = n0 + j * 16 + col;
#pragma unroll
    for (int r = 0; r < 4; ++r) {
      const int m = m0 + w * 16 + rq * 4 + r;
      const int bi = m >> 6, t = m & 63;
      unsafeAtomicAdd(&C[(size_t)(t * BB + bi) * 512 + n], acc[j][r]);
    }
  }
}

// ---------------------------------------------------------------------------
extern "C" void kernel_launch(void* const* d_in, const int* in_sizes, int n_in,
                              void* d_out, int out_size, void* d_ws, size_t ws_size,
                              hipStream_t stream) {
  const float* dec  = (const float*)d_in[0];
  const float* enc  = (const float*)d_in[1];
  const float* cov  = (const float*)d_in[2];
  const float* Wq   = (const float*)d_in[3];
  const float* bq   = (const float*)d_in[4];
  const float* Wc   = (const float*)d_in[5];
  const float* v    = (const float*)d_in[6];
  const float* Wo   = (const float*)d_in[7];
  const float* bo   = (const float*)d_in[8];
  const float* wcov = (const float*)d_in[9];

  float* out = (float*)d_out;
  float* attn_h    = out;                         // [T,B,H]
  float* align_out = out + (size_t)TT * BB * HH;  // [T,B,S]

  char* w = (char*)d_ws;
  const size_t MB = 1024 * 1024;
  unsigned short* encpb   = (unsigned short*)(w);                      // 4 MB
  unsigned short* WqT     = (unsigned short*)(w + 4 * MB);             // 0.5 MB
  unsigned short* WcT     = (unsigned short*)(w + 4 * MB + 512 * 1024);// 0.5 MB
  unsigned short* WoT     = (unsigned short*)(w + 5 * MB);             // 1 MB [n][1024]
  unsigned short* concatb = (unsigned short*)(w + 6 * MB);             // 1 MB [b*64+t][1024]
  float*          Ea1     = (float*)(w + 7 * MB);                      // 1 MB
  float*          Ea2     = (float*)(w + 8 * MB);                      // 8 MB

  k_prep<<<3328, 256, 0, stream>>>(enc, cov, wcov, dec, Wq, Wc, Wo,
                                   encpb, concatb, WqT, WcT, WoT);
  k_gemm12<<<640, 256, 0, stream>>>(concatb, encpb, WqT, WcT, WoT, bq, bo,
                                    Ea1, Ea2, attn_h);
  k_attn<<<256, 1024, 0, stream>>>(Ea1, Ea2, v, encpb, align_out, concatb);
  k_out<<<256, 256, 0, stream>>>(concatb, WoT, attn_h);
}

// Round 10
// 124.041 us; speedup vs baseline: 1.1421x; 1.0177x over previous
//
#include <hip/hip_runtime.h>
#include <cstddef>

static constexpr int TT = 64;    // decoder steps
static constexpr int BB = 8;     // batch
static constexpr int SS = 512;   // source length
static constexpr int HH = 512;   // hidden

typedef __attribute__((ext_vector_type(8))) short bf16x8;
typedef __attribute__((ext_vector_type(4))) float f32x4;

__device__ __forceinline__ float fast_tanh(float x) {
  float e = __expf(2.0f * x);
  return 1.0f - 2.0f * __builtin_amdgcn_rcpf(e + 1.0f);
}
__device__ __forceinline__ unsigned short f2bf(float f) {
  unsigned u = __float_as_uint(f);
  return (unsigned short)((u + 0x7FFFu + ((u >> 16) & 1u)) >> 16);   // RNE
}

// ---------------------------------------------------------------------------
// k_prep — all preprocessing, vectorized (float4/ushort4):
//  [0,2048):     encpb = bf16(tanh(enc + cov*wcov)), 2 bs-rows/block
//  [2048,2304):  dec pack -> concatb right half, 2 m-rows/block
//  [2304,3328):  weight transposes Wq,Wc,Wo (32x32 tiles -> WT[n][k] bf16)
// ---------------------------------------------------------------------------
__global__ __launch_bounds__(256)
void k_prep(const float* __restrict__ enc, const float* __restrict__ cov,
            const float* __restrict__ wcov, const float* __restrict__ dec,
            const float* __restrict__ Wq, const float* __restrict__ Wc,
            const float* __restrict__ Wo,
            unsigned short* __restrict__ encpb, unsigned short* __restrict__ concatb,
            unsigned short* __restrict__ WqT, unsigned short* __restrict__ WcT,
            unsigned short* __restrict__ WoT) {
  __shared__ float tile[32][33];
  const int blk = blockIdx.x, tid = threadIdx.x;

  if (blk < 2048) {
    const int r = tid >> 7, c = (tid & 127) * 4;
    const int bs = blk * 2 + r;
    const int s = bs & 511, b = bs >> 9;
    const float4 ev = *(const float4*)(enc + (size_t)(s * BB + b) * HH + c);
    const float cv = cov[bs];
    const float4 wv = *(const float4*)(wcov + c);
    ushort4 o;
    o.x = f2bf(fast_tanh(ev.x + cv * wv.x));
    o.y = f2bf(fast_tanh(ev.y + cv * wv.y));
    o.z = f2bf(fast_tanh(ev.z + cv * wv.z));
    o.w = f2bf(fast_tanh(ev.w + cv * wv.w));
    *(ushort4*)(encpb + (size_t)bs * HH + c) = o;
  } else if (blk < 2304) {
    const int r = tid >> 7, c = (tid & 127) * 4;
    const int m = (blk - 2048) * 2 + r, t = m & 63, b = m >> 6;   // m = b*64+t
    const float4 dv = *(const float4*)(dec + (size_t)(t * BB + b) * HH + c);
    ushort4 o;
    o.x = f2bf(dv.x); o.y = f2bf(dv.y); o.z = f2bf(dv.z); o.w = f2bf(dv.w);
    *(ushort4*)(concatb + (size_t)m * 1024 + 512 + c) = o;
  } else {
    int l = blk - 2304;
    const float* W; unsigned short* WT; int KT;
    if (l < 256)      { W = Wq; WT = WqT; KT = 512; }
    else if (l < 512) { W = Wc; WT = WcT; KT = 512; l -= 256; }
    else              { W = Wo; WT = WoT; KT = 1024; l -= 512; }
    const int n0 = (l & 15) * 32, k0 = (l >> 4) * 32;
    const int r = tid >> 3, c4 = (tid & 7) * 4;
    const float4 w = *(const float4*)(W + (size_t)(k0 + r) * 512 + n0 + c4);
    tile[r][c4 + 0] = w.x; tile[r][c4 + 1] = w.y;
    tile[r][c4 + 2] = w.z; tile[r][c4 + 3] = w.w;
    __syncthreads();
    unsigned short* o = WT + (size_t)(n0 + r) * KT + k0 + c4;
#pragma unroll
    for (int i = 0; i < 4; ++i) o[i] = f2bf(tile[c4 + i][r]);
  }
}

// ---------------------------------------------------------------------------
// 64x64 bf16 MFMA tile over K range. 256 thr / 4 waves.
// C/D layout: col=lane&15, row=(lane>>4)*4+reg (verified r2..r9).
// ---------------------------------------------------------------------------
template<int LDA, int LDB>
__device__ __forceinline__ void gemm_tile(const unsigned short* __restrict__ A,
                                          const unsigned short* __restrict__ BT,
                                          int m0, int n0, int kbeg, int kend,
                                          unsigned short (*As)[72],
                                          unsigned short (*Bs)[72],
                                          f32x4 acc[4]) {
  const int tid = threadIdx.x, w = tid >> 6, lane = tid & 63;
  const int lr = tid >> 2, lk = (tid & 3) * 16;
  const int fm = w * 16 + (lane & 15), fk = (lane >> 4) * 8;
  for (int k0 = kbeg; k0 < kend; k0 += 64) {
    const uint4* ga = (const uint4*)(A + (size_t)(m0 + lr) * LDA + k0 + lk);
    const uint4* gb = (const uint4*)(BT + (size_t)(n0 + lr) * LDB + k0 + lk);
    uint4 a0 = ga[0], a1 = ga[1], b0 = gb[0], b1 = gb[1];
    *(uint4*)&As[lr][lk] = a0;  *(uint4*)&As[lr][lk + 8] = a1;
    *(uint4*)&Bs[lr][lk] = b0;  *(uint4*)&Bs[lr][lk + 8] = b1;
    __syncthreads();
#pragma unroll
    for (int ks = 0; ks < 2; ++ks) {
      bf16x8 af = *(const bf16x8*)&As[fm][ks * 32 + fk];
#pragma unroll
      for (int j = 0; j < 4; ++j) {
        bf16x8 bf = *(const bf16x8*)&Bs[j * 16 + (lane & 15)][ks * 32 + fk];
        acc[j] = __builtin_amdgcn_mfma_f32_16x16x32_bf16(af, bf, acc[j], 0, 0, 0);
      }
    }
    __syncthreads();
  }
}

// ---------------------------------------------------------------------------
// k_gemm12 — three GEMM jobs in ONE launch (640 blocks):
//  g <  64: Ea1 (fp32) = exp(2*clamp(dec@Wq + bq, +-10.5))
//  g < 576: Ea2b (BF16) = exp(2*clamp(encp@Wc, +-10.5))   <- halves L2 stream
//  g < 640: attn_h base = dec@Wo_bot + bo (scattered [T,B,H]); k_out adds c@Wo_top
// clamp +-10.5: pair-product (Ea1*Ea2+1)^2 <= 2.9e36 finite; tanh(10.5)=1-1.5e-9.
// bf16 Ea2 rel err 0.4% -> dtanh <= 0.002 -> output err ~+0.005, safe vs 0.095.
// ---------------------------------------------------------------------------
__global__ __launch_bounds__(256)
void k_gemm12(const unsigned short* __restrict__ concatb,
              const unsigned short* __restrict__ encpb,
              const unsigned short* __restrict__ WqT,
              const unsigned short* __restrict__ WcT,
              const unsigned short* __restrict__ WoT,
              const float* __restrict__ bq, const float* __restrict__ bo,
              float* __restrict__ Ea1, unsigned short* __restrict__ Ea2b,
              float* __restrict__ attn_h) {
  __shared__ unsigned short As[64][72];
  __shared__ unsigned short Bs[64][72];
  const int g = blockIdx.x, tid = threadIdx.x;
  const int w = tid >> 6, lane = tid & 63;
  const int col = lane & 15, rq = lane >> 4;

  if (g < 64) {                        // a1
    const int m0 = (g >> 3) * 64, n0 = (g & 7) * 64;
    f32x4 acc[4] = {};
    gemm_tile<1024, 512>(concatb + 512, WqT, m0, n0, 0, 512, As, Bs, acc);
#pragma unroll
    for (int j = 0; j < 4; ++j) {
      const int n = n0 + j * 16 + col;
      const float bv = bq[n];
#pragma unroll
      for (int r = 0; r < 4; ++r) {
        const int m = m0 + w * 16 + rq * 4 + r;
        float val = fminf(fmaxf(acc[j][r] + bv, -10.5f), 10.5f);
        Ea1[(size_t)m * 512 + n] = __expf(2.0f * val);
      }
    }
  } else if (g < 576) {                // a2 -> bf16
    const int u = g - 64;
    const int m0 = (u >> 3) * 64, n0 = (u & 7) * 64;
    f32x4 acc[4] = {};
    gemm_tile<512, 512>(encpb, WcT, m0, n0, 0, 512, As, Bs, acc);
#pragma unroll
    for (int j = 0; j < 4; ++j) {
      const int n = n0 + j * 16 + col;
#pragma unroll
      for (int r = 0; r < 4; ++r) {
        const int m = m0 + w * 16 + rq * 4 + r;
        float val = fminf(fmaxf(acc[j][r], -10.5f), 10.5f);
        Ea2b[(size_t)m * 512 + n] = f2bf(__expf(2.0f * val));
      }
    }
  } else {                             // attn_h base = dec@Wo_bot + bo
    const int u = g - 576;
    const int m0 = (u >> 3) * 64, n0 = (u & 7) * 64;
    f32x4 acc[4] = {};
    gemm_tile<1024, 1024>(concatb, WoT, m0, n0, 512, 1024, As, Bs, acc);
#pragma unroll
    for (int j = 0; j < 4; ++j) {
      const int n = n0 + j * 16 + col;
      const float bv = bo[n];
#pragma unroll
      for (int r = 0; r < 4; ++r) {
        const int m = m0 + w * 16 + rq * 4 + r;
        const int bi = m >> 6, t = m & 63;
        attn_h[(size_t)(t * BB + bi) * 512 + n] = acc[j][r] + bv;
      }
    }
  }
}

// ---------------------------------------------------------------------------
// k_attn — scores + softmax + context; 256 blocks (b, t-pair), 1024 thr.
// Scores (pair-rcp, bf16 Ea2): one uint4 load = 8 Ea2 elems; unpack via
// shift/mask (bf16->fp32 is exact). ea1s/v2s stay FP32 in LDS (bf16 there
// would push unpack onto the limiting VALU pipe — checked, net loss).
// sc = -(sum_h 2 v_h/(Ea1*Ea2+1))  [softmax shift-invariant].
// ---------------------------------------------------------------------------
__global__ __launch_bounds__(1024)
void k_attn(const float* __restrict__ Ea1, const unsigned short* __restrict__ Ea2b,
            const float* __restrict__ v, const unsigned short* __restrict__ encpb,
            float* __restrict__ align_out, unsigned short* __restrict__ concatb) {
  __shared__ __align__(16) char smem[20544];
  float (*sc)[512]   = (float(*)[512])smem;            // [2][512] scores->align
  float (*ea1s)[512] = (float(*)[512])(smem + 4096);   // [2][512] (scores phase)
  float* v2s         = (float*)(smem + 12288);         // [512]    (scores phase)
  float2* part       = (float2*)(smem + 4096);         // [2][4][256] (ctx phase)
  float (*red)[8]    = (float(*)[8])(smem + 20480);    // [2][8]

  const int g = blockIdx.x, tid = threadIdx.x;
  const int b = g & 7, t0 = (g >> 3) * 2;              // XCD-affine b
  const int wv = tid >> 6, lane = tid & 63;
  const int hq = lane & 3, sl = lane >> 2;

  if (tid < 512) {
    ea1s[0][tid] = Ea1[(size_t)(b * TT + t0) * HH + tid];
    ea1s[1][tid] = Ea1[(size_t)(b * TT + t0 + 1) * HH + tid];
  } else {
    v2s[tid - 512] = 2.0f * v[tid - 512];
  }
  __syncthreads();

  // ---- scores: 16 waves x 32 s, one pass; 32-h chunks (8 bf16/lane-load) ----
  const int s0 = wv * 32 + sl;                         // and s0+16
  {
    const unsigned short* e2r0 = Ea2b + (size_t)(b * SS + s0) * HH;
    const unsigned short* e2r1 = e2r0 + (size_t)16 * HH;
    float acc[2][2] = {};
#define BFLO(u) __uint_as_float((u) << 16)
#define BFHI(u) __uint_as_float((u) & 0xffff0000u)
#define PAIR(E1a, E2a, Va, E1b, E2b, Vb, A)                                  \
    {                                                                        \
      const float x1 = fmaf(E1a, E2a, 1.0f), x2 = fmaf(E1b, E2b, 1.0f);      \
      const float rr = __builtin_amdgcn_rcpf(x1 * x2);                       \
      const float nn = fmaf(Va, x2, Vb * x1);                                \
      A = fmaf(nn, rr, A);                                                   \
    }
#pragma unroll 4
    for (int it = 0; it < 16; ++it) {
      const int h = it * 32 + hq * 8;
      const uint4 u0 = *(const uint4*)(e2r0 + h);
      const uint4 u1 = *(const uint4*)(e2r1 + h);
      const float4 va = *(const float4*)&v2s[h];
      const float4 vb = *(const float4*)&v2s[h + 4];
      float4 e1a[2], e1b[2];
      e1a[0] = *(const float4*)&ea1s[0][h]; e1b[0] = *(const float4*)&ea1s[0][h + 4];
      e1a[1] = *(const float4*)&ea1s[1][h]; e1b[1] = *(const float4*)&ea1s[1][h + 4];
#pragma unroll
      for (int i = 0; i < 2; ++i) {
        PAIR(e1a[i].x, BFLO(u0.x), va.x, e1a[i].y, BFHI(u0.x), va.y, acc[i][0]);
        PAIR(e1a[i].z, BFLO(u0.y), va.z, e1a[i].w, BFHI(u0.y), va.w, acc[i][0]);
        PAIR(e1b[i].x, BFLO(u0.z), vb.x, e1b[i].y, BFHI(u0.z), vb.y, acc[i][0]);
        PAIR(e1b[i].z, BFLO(u0.w), vb.z, e1b[i].w, BFHI(u0.w), vb.w, acc[i][0]);
        PAIR(e1a[i].x, BFLO(u1.x), va.x, e1a[i].y, BFHI(u1.x), va.y, acc[i][1]);
        PAIR(e1a[i].z, BFLO(u1.y), va.z, e1a[i].w, BFHI(u1.y), va.w, acc[i][1]);
        PAIR(e1b[i].x, BFLO(u1.z), vb.x, e1b[i].y, BFHI(u1.z), vb.y, acc[i][1]);
        PAIR(e1b[i].z, BFLO(u1.w), vb.z, e1b[i].w, BFHI(u1.w), vb.w, acc[i][1]);
      }
    }
#undef PAIR
#undef BFLO
#undef BFHI
#pragma unroll
    for (int i = 0; i < 2; ++i)
#pragma unroll
      for (int j = 0; j < 2; ++j) {
        acc[i][j] += __shfl_xor(acc[i][j], 1);
        acc[i][j] += __shfl_xor(acc[i][j], 2);
      }
    if (hq == 0) {
      sc[0][s0] = -acc[0][0]; sc[0][s0 + 16] = -acc[0][1];
      sc[1][s0] = -acc[1][0]; sc[1][s0 + 16] = -acc[1][1];
    }
  }
  __syncthreads();

  // ---- softmax over s (threads < 512 own s=tid; all threads hit barriers) --
  float x0 = 0.f, x1 = 0.f, e0 = 0.f, e1 = 0.f;
  if (tid < 512) {
    x0 = sc[0][tid]; x1 = sc[1][tid];
    float m0 = x0, m1 = x1;
#pragma unroll
    for (int off = 32; off; off >>= 1) {
      m0 = fmaxf(m0, __shfl_xor(m0, off));
      m1 = fmaxf(m1, __shfl_xor(m1, off));
    }
    if (lane == 0) { red[0][wv] = m0; red[1][wv] = m1; }
  }
  __syncthreads();
  {
    float m0 = red[0][0], m1 = red[1][0];
#pragma unroll
    for (int w2 = 1; w2 < 8; ++w2) { m0 = fmaxf(m0, red[0][w2]); m1 = fmaxf(m1, red[1][w2]); }
    __syncthreads();
    if (tid < 512) {
      e0 = __expf(x0 - m0); e1 = __expf(x1 - m1);
      float s0v = e0, s1v = e1;
#pragma unroll
      for (int off = 32; off; off >>= 1) {
        s0v += __shfl_xor(s0v, off);
        s1v += __shfl_xor(s1v, off);
      }
      if (lane == 0) { red[0][wv] = s0v; red[1][wv] = s1v; }
    }
  }
  __syncthreads();
  {
    float sum0 = 0.f, sum1 = 0.f;
#pragma unroll
    for (int w2 = 0; w2 < 8; ++w2) { sum0 += red[0][w2]; sum1 += red[1][w2]; }
    if (tid < 512) {
      const float a0 = e0 * __builtin_amdgcn_rcpf(sum0);
      const float a1 = e1 * __builtin_amdgcn_rcpf(sum1);
      align_out[(size_t)(t0 + 0) * BB * SS + b * SS + tid] = a0;
      align_out[(size_t)(t0 + 1) * BB * SS + b * SS + tid] = a1;
      sc[0][tid] = a0;
      sc[1][tid] = a1;
    }
  }
  __syncthreads();

  // ---- context: q = s-quarter (tid>>8), hp = h-pair (tid&255) ----
  {
    const int q = tid >> 8, hp = tid & 255;
    const unsigned* ep = (const unsigned*)encpb + (size_t)b * SS * 256;
    float c00 = 0.f, c01 = 0.f, c10 = 0.f, c11 = 0.f;
#pragma unroll 8
    for (int s2 = q * 128; s2 < q * 128 + 128; ++s2) {
      const unsigned u = ep[s2 * 256 + hp];
      const float elo = __uint_as_float(u << 16);
      const float ehi = __uint_as_float(u & 0xffff0000u);
      const float av0 = sc[0][s2], av1 = sc[1][s2];
      c00 = fmaf(av0, elo, c00); c01 = fmaf(av0, ehi, c01);
      c10 = fmaf(av1, elo, c10); c11 = fmaf(av1, ehi, c11);
    }
    part[(0 * 4 + q) * 256 + hp] = make_float2(c00, c01);
    part[(1 * 4 + q) * 256 + hp] = make_float2(c10, c11);
  }
  __syncthreads();
  if (tid < 512) {
    const int t = tid >> 8, hp = tid & 255;
    float clo = 0.f, chi = 0.f;
#pragma unroll
    for (int q = 0; q < 4; ++q) {
      const float2 p = part[(t * 4 + q) * 256 + hp];
      clo += p.x; chi += p.y;
    }
    ((unsigned*)concatb)[(size_t)(b * TT + t0 + t) * 512 + hp] =
        (unsigned)f2bf(clo) | ((unsigned)f2bf(chi) << 16);
  }
}

// ---------------------------------------------------------------------------
// k_out — attn_h += c@Wo_top (K=512), split-K x4 via HW fp32 atomics on the
// base (dec@Wo_bot + bo) written by k_gemm12. 256 blocks.
// ---------------------------------------------------------------------------
__global__ __launch_bounds__(256)
void k_out(const unsigned short* __restrict__ A,
           const unsigned short* __restrict__ BT,
           float* __restrict__ C) {
  __shared__ unsigned short As[64][72];
  __shared__ unsigned short Bs[64][72];
  const int tid = threadIdx.x;
  const int w = tid >> 6, lane = tid & 63;
  const int tau = blockIdx.x >> 2, kc = blockIdx.x & 3;
  const int n0 = (tau & 7) * 64, m0 = (tau >> 3) * 64;

  f32x4 acc[4] = {};
  gemm_tile<1024, 1024>(A, BT, m0, n0, kc * 128, kc * 128 + 128, As, Bs, acc);

  const int col = lane & 15, rq = lane >> 4;
#pragma unroll
  for (int j = 0; j < 4; ++j) {
    const int n = n0 + j * 16 + col;
#pragma unroll
    for (int r = 0; r < 4; ++r) {
      const int m = m0 + w * 16 + rq * 4 + r;
      const int bi = m >> 6, t = m & 63;
      unsafeAtomicAdd(&C[(size_t)(t * BB + bi) * 512 + n], acc[j][r]);
    }
  }
}

// ---------------------------------------------------------------------------
extern "C" void kernel_launch(void* const* d_in, const int* in_sizes, int n_in,
                              void* d_out, int out_size, void* d_ws, size_t ws_size,
                              hipStream_t stream) {
  const float* dec  = (const float*)d_in[0];
  const float* enc  = (const float*)d_in[1];
  const float* cov  = (const float*)d_in[2];
  const float* Wq   = (const float*)d_in[3];
  const float* bq   = (const float*)d_in[4];
  const float* Wc   = (const float*)d_in[5];
  const float* v    = (const float*)d_in[6];
  const float* Wo   = (const float*)d_in[7];
  const float* bo   = (const float*)d_in[8];
  const float* wcov = (const float*)d_in[9];

  float* out = (float*)d_out;
  float* attn_h    = out;                         // [T,B,H]
  float* align_out = out + (size_t)TT * BB * HH;  // [T,B,S]

  char* w = (char*)d_ws;
  const size_t MB = 1024 * 1024;
  unsigned short* encpb   = (unsigned short*)(w);                      // 4 MB
  unsigned short* WqT     = (unsigned short*)(w + 4 * MB);             // 0.5 MB
  unsigned short* WcT     = (unsigned short*)(w + 4 * MB + 512 * 1024);// 0.5 MB
  unsigned short* WoT     = (unsigned short*)(w + 5 * MB);             // 1 MB [n][1024]
  unsigned short* concatb = (unsigned short*)(w + 6 * MB);             // 1 MB [b*64+t][1024]
  float*          Ea1     = (float*)(w + 7 * MB);                      // 1 MB
  unsigned short* Ea2b    = (unsigned short*)(w + 8 * MB);             // 4 MB bf16

  k_prep<<<3328, 256, 0, stream>>>(enc, cov, wcov, dec, Wq, Wc, Wo,
                                   encpb, concatb, WqT, WcT, WoT);
  k_gemm12<<<640, 256, 0, stream>>>(concatb, encpb, WqT, WcT, WoT, bq, bo,
                                    Ea1, Ea2b, attn_h);
  k_attn<<<256, 1024, 0, stream>>>(Ea1, Ea2b, v, encpb, align_out, concatb);
  k_out<<<256, 256, 0, stream>>>(concatb, WoT, attn_h);
}